// Round 1
// baseline (379.590 us; speedup 1.0000x reference)
//
#include <hip/hip_runtime.h>

typedef _Float16 half8 __attribute__((ext_vector_type(8)));
typedef float floatx4 __attribute__((ext_vector_type(4)));

constexpr int IN_F  = 8192;
constexpr int OUT_F = 8192;
constexpr int NCOL  = 16;

constexpr int WVS     = 8;               // waves per block (512 threads)
constexpr int KCHUNK  = IN_F / WVS;      // 1024 k per wave
constexpr int SUBK    = 128;             // k per register-resident B group
constexpr int NSUB    = KCHUNK / SUBK;   // 8
constexpr int STEPS   = SUBK / 32;       // 4 MFMA k-steps per group
constexpr int NBLOCKS = OUT_F / 16;      // 512: one 16-row tile per block, full K

// D = W @ x. W as MFMA A-operand (16 rows), x as B (16 cols), fp32 acc.
// Layouts (gfx950, HW-verified in prior session): A[m=lane&15][k=quad*8+j],
// B[k=quad*8+j][n=lane&15], C/D: col=lane&15, row=quad*4+reg.
//
// K-split is INTRA-block: 8 waves own disjoint 1024-k chunks of the same
// 16-row tile; partials meet in an 8 KB LDS reduction -> one non-atomic,
// coalesced store. No atomics, no output pre-zeroing, deterministic.
__global__ __launch_bounds__(512, 4)
void lq_mfma_kernel(const float* __restrict__ x,
                    const void* __restrict__ wraw,
                    const float* __restrict__ scaler,
                    float* __restrict__ out)
{
    __shared__ float red[WVS * 256];     // 8 waves x (16 rows x 16 cols)

    const int tid  = threadIdx.x;
    const int lane = tid & 63;
    const int wv   = tid >> 6;
    const int m    = lane & 15;          // A row-in-tile == C col
    const int quad = lane >> 4;
    const int row0 = blockIdx.x * 16;
    const int k0   = wv * KCHUNK;

    // ---- dtype probe: int32-materialized weights vs raw int8 (wave-uniform,
    // same cache line for every wave; verified in prior session) ----
    const int* wi = (const int*)wraw;
    bool w_is_i32 = true;
    #pragma unroll
    for (int i = 0; i < 16; ++i) {
        int v = wi[i];
        w_is_i32 = w_is_i32 && (v >= -128) && (v <= 127);
    }

    const float* xp = x + (size_t)(k0 + quad * 8) * NCOL + m;
    floatx4 acc = {0.f, 0.f, 0.f, 0.f};

    if (w_is_i32) {
        // ---- path A: weights materialized as int32 (268 MB stream) ----
        const int* wrow = (const int*)wraw + (size_t)(row0 + m) * IN_F + k0 + quad * 8;
        #pragma unroll 1
        for (int sc = 0; sc < NSUB; ++sc) {
            const int kb = sc * SUBK;
            half8 bf[STEPS];
            #pragma unroll
            for (int st = 0; st < STEPS; ++st) {
                #pragma unroll
                for (int j = 0; j < 8; ++j)
                    bf[st][j] = (_Float16)xp[(kb + st * 32 + j) * NCOL];
            }
            #pragma unroll
            for (int st = 0; st < STEPS; ++st) {
                half8 af;
                #pragma unroll
                for (int j = 0; j < 8; ++j)
                    af[j] = (_Float16)wrow[kb + st * 32 + j];   // 2x dwordx4/lane
                acc = __builtin_amdgcn_mfma_f32_16x16x32_f16(af, bf[st], acc, 0, 0, 0);
            }
        }
    } else {
        // ---- path B: weights raw int8 (64 MB stream) ----
        const signed char* wrow = (const signed char*)wraw + (size_t)(row0 + m) * IN_F + k0 + quad * 8;
        #pragma unroll 1
        for (int sc = 0; sc < NSUB; ++sc) {
            const int kb = sc * SUBK;
            half8 bf[STEPS];
            #pragma unroll
            for (int st = 0; st < STEPS; ++st) {
                #pragma unroll
                for (int j = 0; j < 8; ++j)
                    bf[st][j] = (_Float16)xp[(kb + st * 32 + j) * NCOL];
            }
            #pragma unroll
            for (int st = 0; st < STEPS; ++st) {
                const uint2 u = *(const uint2*)(wrow + kb + st * 32);  // 8 int8/lane
                half8 af;
                #pragma unroll
                for (int j = 0; j < 4; ++j) {
                    af[j]     = (_Float16)(int)(signed char)(u.x >> (8 * j));
                    af[j + 4] = (_Float16)(int)(signed char)(u.y >> (8 * j));
                }
                acc = __builtin_amdgcn_mfma_f32_16x16x32_f16(af, bf[st], acc, 0, 0, 0);
            }
        }
    }

    // ---- cross-wave reduction in LDS, single coalesced store ----
    #pragma unroll
    for (int g = 0; g < 4; ++g)
        red[wv * 256 + (quad * 4 + g) * 16 + m] = acc[g];
    __syncthreads();

    if (tid < 256) {
        float sum = 0.f;
        #pragma unroll
        for (int v = 0; v < WVS; ++v)
            sum += red[v * 256 + tid];
        out[(size_t)(row0 + (tid >> 4)) * NCOL + (tid & 15)] = sum * scaler[0];
    }
}

extern "C" void kernel_launch(void* const* d_in, const int* in_sizes, int n_in,
                              void* d_out, int out_size, void* d_ws, size_t ws_size,
                              hipStream_t stream)
{
    const float* x      = (const float*)d_in[0];
    const void*  w      = d_in[1];
    const float* scaler = (const float*)d_in[2];
    float*       out    = (float*)d_out;

    // No K-split across blocks -> no atomics -> no output pre-zeroing.
    lq_mfma_kernel<<<NBLOCKS, 512, 0, stream>>>(x, w, scaler, out);
}